// Round 1
// baseline (233.687 us; speedup 1.0000x reference)
//
#include <hip/hip_runtime.h>
#include <hip/hip_bf16.h>
#include <stdint.h>

// Problem constants (from reference)
#define T_DIM   4
#define N_GRID  12288
#define C_DIM   16
#define NH      9
#define N_OUT   1024        // UP*E
#define K_DIM   144         // NH*C
#define M_TOTAL 196608      // B*V*T*N_GRID

#define BM        64        // rows per block tile
#define AS_STRIDE 148       // padded LDS row stride (f16 elems)
#define KSTEPS    18        // 144 / 8

typedef __attribute__((ext_vector_type(4)))  float    f32x4;
typedef __attribute__((ext_vector_type(16))) float    f32x16;
typedef __attribute__((ext_vector_type(4)))  _Float16 f16x4;
typedef __attribute__((ext_vector_type(8)))  _Float16 f16x8;

// ---------------------------------------------------------------------------
// Pre-pass: convert W (144x1024 f32) to f16, packed in MFMA B-fragment order.
// Layout: Wpk[((s*16 + q)*64 + lane)*8 + e], e = cgoff*4 + j
//   value = f16( W[(8*s + 4*(lane>>5) + j) * 1024 + q*64 + cgoff*32 + (lane&31)] )
// s = K-step (0..17), q = 64-col group (0..15).
// ---------------------------------------------------------------------------
__global__ void pack_w_kernel(const float* __restrict__ W,
                              _Float16* __restrict__ Wpk) {
    const int gid = blockIdx.x * blockDim.x + threadIdx.x;   // 0..18431
    const int lane = gid & 63;
    const int q    = (gid >> 6) & 15;
    const int s    = gid >> 10;          // 0..17
    const int l31  = lane & 31;
    const int lhi  = lane >> 5;

    _Float16 v[8];
#pragma unroll
    for (int e = 0; e < 8; ++e) {
        const int cgoff = e >> 2;
        const int j     = e & 3;
        const int k     = 8 * s + 4 * lhi + j;            // 0..143
        const int col   = q * 64 + cgoff * 32 + l31;      // 0..1023
        v[e] = (_Float16)W[k * N_OUT + col];
    }
    *(f16x8*)(Wpk + (size_t)gid * 8) = *(const f16x8*)v;
}

// ---------------------------------------------------------------------------
// Main kernel: gather A-tile (64 rows x 144) into LDS as f16, then GEMM with
// v_mfma_f32_32x32x8_f16. Block = 256 threads (4 waves).
// Tile: 64 rows x 256 cols; wave w owns cols [ (ntile*4+w)*64 , +64 ).
// ---------------------------------------------------------------------------
__global__ __launch_bounds__(256) void mg_gemm_kernel(
    const float* __restrict__ mg,       // (8, 4, 12288, 16) f32
    const int*   __restrict__ vidx,     // (1, 4)
    const int*   __restrict__ adjc,     // (12288, 9)
    const _Float16* __restrict__ Wpk,   // packed B fragments
    const float* __restrict__ bias,     // (1024,)
    float* __restrict__ out)            // (196608, 1024) f32
{
    __shared__ _Float16 As[BM * AS_STRIDE];

    const int mtile = blockIdx.x;          // 0..3071
    const int ntile = blockIdx.y;          // 0..3
    const int r0    = mtile * BM;          // global row base
    const int v     = r0 / (T_DIM * N_GRID);
    const int t     = (r0 / N_GRID) & 3;
    const int p0    = r0 % N_GRID;
    const int vi    = vidx[v];
    const float* src = mg + (size_t)(vi * T_DIM + t) * N_GRID * C_DIM;

    const int tid = threadIdx.x;

    // ---- stage A tile: 64 rows x 9 neighbors x 16 channels -> f16 LDS ----
    for (int task = tid; task < BM * NH; task += 256) {
        const int row = task / NH;
        const int nh  = task - row * NH;
        const int g   = adjc[p0 * NH + task];        // == adjc[(p0+row)*9 + nh]
        const float* sp = src + (size_t)g * C_DIM;
        _Float16* dst = &As[row * AS_STRIDE + nh * C_DIM];
#pragma unroll
        for (int c4 = 0; c4 < 4; ++c4) {
            f32x4 f = *(const f32x4*)(sp + 4 * c4);
            f16x4 h = __builtin_convertvector(f, f16x4);
            *(f16x4*)(dst + 4 * c4) = h;
        }
    }
    __syncthreads();

    const int lane = tid & 63;
    const int w    = tid >> 6;             // wave id 0..3
    const int l31  = lane & 31;
    const int lhi  = lane >> 5;
    const int q    = ntile * 4 + w;        // 64-col group 0..15

    f32x16 acc00, acc01, acc10, acc11;     // [cg][rowhalf]
#pragma unroll
    for (int i = 0; i < 16; ++i) { acc00[i]=0.f; acc01[i]=0.f; acc10[i]=0.f; acc11[i]=0.f; }

    const _Float16* arow0 = &As[l31 * AS_STRIDE + 4 * lhi];
    const _Float16* arow1 = arow0 + 32 * AS_STRIDE;
    const _Float16* wp    = Wpk + ((size_t)q * 64 + lane) * 8;

#pragma unroll
    for (int s = 0; s < KSTEPS; ++s) {
        const int aoff = (s >> 1) * 16 + (s & 1) * 8;   // nh*16 + (s&1)*8
        f16x4 a0 = *(const f16x4*)(arow0 + aoff);
        f16x4 a1 = *(const f16x4*)(arow1 + aoff);
        union { f16x8 v8; f16x4 v4[2]; } bu;
        bu.v8 = *(const f16x8*)(wp + (size_t)s * (16 * 64 * 8));
        acc00 = __builtin_amdgcn_mfma_f32_32x32x8f16(a0, bu.v4[0], acc00, 0, 0, 0);
        acc01 = __builtin_amdgcn_mfma_f32_32x32x8f16(a1, bu.v4[0], acc01, 0, 0, 0);
        acc10 = __builtin_amdgcn_mfma_f32_32x32x8f16(a0, bu.v4[1], acc10, 0, 0, 0);
        acc11 = __builtin_amdgcn_mfma_f32_32x32x8f16(a1, bu.v4[1], acc11, 0, 0, 0);
    }

    // ---- epilogue: add bias, store f32 ----
    const int colbase = q * 64 + l31;
    const float b0f = bias[colbase];
    const float b1f = bias[colbase + 32];
    float* outp = out + (size_t)r0 * N_OUT;

#pragma unroll
    for (int r = 0; r < 16; ++r) {
        const int rr = (r & 3) + 8 * (r >> 2) + 4 * lhi;   // 0..31
        outp[(size_t)rr * N_OUT + colbase]             = acc00[r] + b0f;
        outp[(size_t)rr * N_OUT + colbase + 32]        = acc10[r] + b1f;
        outp[(size_t)(rr + 32) * N_OUT + colbase]      = acc01[r] + b0f;
        outp[(size_t)(rr + 32) * N_OUT + colbase + 32] = acc11[r] + b1f;
    }
}

// ---------------------------------------------------------------------------
extern "C" void kernel_launch(void* const* d_in, const int* in_sizes, int n_in,
                              void* d_out, int out_size, void* d_ws, size_t ws_size,
                              hipStream_t stream) {
    const float* mg   = (const float*)d_in[0];   // mg_emb
    const int*   vidx = (const int*)  d_in[1];   // var_indices
    const int*   adjc = (const int*)  d_in[2];   // adjc
    const float* W    = (const float*)d_in[3];   // W
    const float* bias = (const float*)d_in[4];   // b
    float*       out  = (float*)d_out;
    _Float16*    Wpk  = (_Float16*)d_ws;         // 294912 bytes needed

    // pre-pack W into MFMA fragment order (18432 threads)
    pack_w_kernel<<<dim3(72), dim3(256), 0, stream>>>(W, Wpk);

    // main gather+GEMM
    mg_gemm_kernel<<<dim3(M_TOTAL / BM, 4), dim3(256), 0, stream>>>(
        mg, vidx, adjc, Wpk, bias, out);
}

// Round 2
// 206.482 us; speedup vs baseline: 1.1318x; 1.1318x over previous
//
#include <hip/hip_runtime.h>
#include <hip/hip_bf16.h>
#include <stdint.h>

// Problem constants (from reference)
#define T_DIM   4
#define N_GRID  12288
#define C_DIM   16
#define NH      9
#define N_OUT   1024        // UP*E
#define K_DIM   144         // NH*C
#define M_TOTAL 196608      // B*V*T*N_GRID

#define BM        64        // rows per block tile
#define BN        512       // cols per block tile (8 waves x 64)
#define AS_STRIDE 152       // padded LDS row stride (f16 elems; 304B, 16B-aligned)
#define KSTEPS    9         // 144 / 16

typedef __attribute__((ext_vector_type(4)))  float    f32x4;
typedef __attribute__((ext_vector_type(16))) float    f32x16;
typedef __attribute__((ext_vector_type(4)))  _Float16 f16x4;
typedef __attribute__((ext_vector_type(8)))  _Float16 f16x8;

// ---------------------------------------------------------------------------
// Pre-pass: convert W (144x1024 f32) to f16, packed in MFMA B-fragment order
// for v_mfma_f32_32x32x16_f16.
// Element index: gid = ((s*16 + q)*64 + lane)*2 + cg ; each gid holds 8 f16:
//   v[j] = f16( W[(16*s + 8*(lane>>5) + j) * 1024 + q*64 + cg*32 + (lane&31)] )
// s = K-step (0..8, = neighbor), q = 64-col group (0..15), cg = 32-col half.
// ---------------------------------------------------------------------------
__global__ void pack_w_kernel(const float* __restrict__ W,
                              _Float16* __restrict__ Wpk) {
    const int gid  = blockIdx.x * blockDim.x + threadIdx.x;  // 0..18431
    const int cg   = gid & 1;
    const int lane = (gid >> 1) & 63;
    const int q    = (gid >> 7) & 15;
    const int s    = gid >> 11;          // 0..8
    const int l31  = lane & 31;
    const int lhi  = lane >> 5;

    _Float16 v[8];
#pragma unroll
    for (int j = 0; j < 8; ++j) {
        const int k   = 16 * s + 8 * lhi + j;             // 0..143
        const int col = q * 64 + cg * 32 + l31;           // 0..1023
        v[j] = (_Float16)W[k * N_OUT + col];
    }
    *(f16x8*)(Wpk + (size_t)gid * 8) = *(const f16x8*)v;
}

// ---------------------------------------------------------------------------
// Main kernel: gather A-tile (64 rows x 144) into LDS as f16, then GEMM with
// v_mfma_f32_32x32x16_f16. Block = 512 threads (8 waves).
// Tile: 64 rows x 512 cols; wave w owns cols [ (ntile*8+w)*64 , +64 ).
// ---------------------------------------------------------------------------
__global__ __launch_bounds__(512, 4) void mg_gemm_kernel(
    const float* __restrict__ mg,       // (8, 4, 12288, 16) f32
    const int*   __restrict__ vidx,     // (1, 4)
    const int*   __restrict__ adjc,     // (12288, 9)
    const _Float16* __restrict__ Wpk,   // packed B fragments
    const float* __restrict__ bias,     // (1024,)
    float* __restrict__ out)            // (196608, 1024) f32
{
    __shared__ _Float16 As[BM * AS_STRIDE];   // 19456 B

    const int mtile = blockIdx.x;          // 0..3071
    const int ntile = blockIdx.y;          // 0..1
    const int r0    = mtile * BM;          // global row base
    const int v     = r0 / (T_DIM * N_GRID);
    const int t     = (r0 / N_GRID) & 3;
    const int p0    = r0 % N_GRID;
    const int vi    = vidx[v];
    const float* src = mg + (size_t)(vi * T_DIM + t) * N_GRID * C_DIM;

    const int tid = threadIdx.x;

    // ---- stage A tile: 64 rows x 9 neighbors x 16 channels -> f16 LDS ----
    for (int task = tid; task < BM * NH; task += BN) {
        const int row = task / NH;
        const int nh  = task - row * NH;
        const int g   = adjc[p0 * NH + task];        // == adjc[(p0+row)*9 + nh]
        const float* sp = src + (size_t)g * C_DIM;
        _Float16* dst = &As[row * AS_STRIDE + nh * C_DIM];
        f32x4 f0 = *(const f32x4*)(sp + 0);
        f32x4 f1 = *(const f32x4*)(sp + 4);
        f32x4 f2 = *(const f32x4*)(sp + 8);
        f32x4 f3 = *(const f32x4*)(sp + 12);
        f16x8 h0, h1;
#pragma unroll
        for (int i = 0; i < 4; ++i) {
            h0[i]     = (_Float16)f0[i];
            h0[i + 4] = (_Float16)f1[i];
            h1[i]     = (_Float16)f2[i];
            h1[i + 4] = (_Float16)f3[i];
        }
        *(f16x8*)(dst + 0) = h0;
        *(f16x8*)(dst + 8) = h1;
    }
    __syncthreads();

    const int lane = tid & 63;
    const int w    = tid >> 6;             // wave id 0..7
    const int l31  = lane & 31;
    const int lhi  = lane >> 5;
    const int q    = ntile * 8 + w;        // 64-col group 0..15

    f32x16 acc00, acc01, acc10, acc11;     // [colhalf][rowhalf]
#pragma unroll
    for (int i = 0; i < 16; ++i) { acc00[i]=0.f; acc01[i]=0.f; acc10[i]=0.f; acc11[i]=0.f; }

    const _Float16* arow0 = &As[l31 * AS_STRIDE + 8 * lhi];
    const _Float16* arow1 = arow0 + 32 * AS_STRIDE;
    const _Float16* wp    = Wpk + ((size_t)q * 64 + lane) * 16;

#pragma unroll
    for (int s = 0; s < KSTEPS; ++s) {
        f16x8 a0 = *(const f16x8*)(arow0 + s * C_DIM);
        f16x8 a1 = *(const f16x8*)(arow1 + s * C_DIM);
        const _Float16* bp = wp + (size_t)s * (16 * 64 * 16);
        f16x8 b0 = *(const f16x8*)(bp + 0);
        f16x8 b1 = *(const f16x8*)(bp + 8);
        acc00 = __builtin_amdgcn_mfma_f32_32x32x16_f16(a0, b0, acc00, 0, 0, 0);
        acc01 = __builtin_amdgcn_mfma_f32_32x32x16_f16(a1, b0, acc01, 0, 0, 0);
        acc10 = __builtin_amdgcn_mfma_f32_32x32x16_f16(a0, b1, acc10, 0, 0, 0);
        acc11 = __builtin_amdgcn_mfma_f32_32x32x16_f16(a1, b1, acc11, 0, 0, 0);
    }

    // ---- epilogue: add bias, non-temporal f32 stores (keep L2 for gathers) --
    const int colbase = q * 64 + l31;
    const float b0f = bias[colbase];
    const float b1f = bias[colbase + 32];
    float* outp = out + (size_t)r0 * N_OUT;

#pragma unroll
    for (int r = 0; r < 16; ++r) {
        const int rr = (r & 3) + 8 * (r >> 2) + 4 * lhi;   // 0..31
        __builtin_nontemporal_store(acc00[r] + b0f, &outp[(size_t)rr * N_OUT + colbase]);
        __builtin_nontemporal_store(acc10[r] + b1f, &outp[(size_t)rr * N_OUT + colbase + 32]);
        __builtin_nontemporal_store(acc01[r] + b0f, &outp[(size_t)(rr + 32) * N_OUT + colbase]);
        __builtin_nontemporal_store(acc11[r] + b1f, &outp[(size_t)(rr + 32) * N_OUT + colbase + 32]);
    }
}

// ---------------------------------------------------------------------------
extern "C" void kernel_launch(void* const* d_in, const int* in_sizes, int n_in,
                              void* d_out, int out_size, void* d_ws, size_t ws_size,
                              hipStream_t stream) {
    const float* mg   = (const float*)d_in[0];   // mg_emb
    const int*   vidx = (const int*)  d_in[1];   // var_indices
    const int*   adjc = (const int*)  d_in[2];   // adjc
    const float* W    = (const float*)d_in[3];   // W
    const float* bias = (const float*)d_in[4];   // b
    float*       out  = (float*)d_out;
    _Float16*    Wpk  = (_Float16*)d_ws;         // 294912 bytes needed

    // pre-pack W into MFMA fragment order (18432 threads)
    pack_w_kernel<<<dim3(72), dim3(256), 0, stream>>>(W, Wpk);

    // main gather+GEMM: 64x512 tiles
    mg_gemm_kernel<<<dim3(M_TOTAL / BM, N_OUT / BN), dim3(512), 0, stream>>>(
        mg, vidx, adjc, Wpk, bias, out);
}